// Round 6
// baseline (57.457 us; speedup 1.0000x reference)
//
#include <hip/hip_runtime.h>
#include <math.h>

namespace {
constexpr int B_ = 4096;
constexpr int C_ = 12288;
constexpr int R_ = 2;                    // rows per block
constexpr float DEG2RAD = 0.017453292519943295f;
constexpr float LOG2E = 1.4426950408889634f;
// w = exp(-2R*asin(s)/tau) = exp2(KN2*asin(s)), KN2 = -(2*6371/75)*log2(e)
constexpr float KN2 = -245.10427f;
// asin(s) ~= s*(1 + a/6), a = s^2. Truncation 0.075*s^5: at s=0.057 (w=1e-6)
// error in exponent = 1e-5 -> invisible. Folded: KN2*asin(s) = s*(C0 + C1*a).
constexpr float C0 = KN2;
constexpr float C1 = KN2 / 6.0f;
}

// Per-centroid HALF unit-sphere coords, interleaved per 4-centroid group:
// group g occupies 12 floats: [x0..x3][y0..y3][z0..z3] -> one address stream.
// Thread 0 also zeroes the output accumulator (runs before row_loss on stream).
__global__ void centroid_xyz_kernel(const float* __restrict__ centroids,
                                    float* __restrict__ ctq,
                                    float* __restrict__ out) {
    int c = blockIdx.x * blockDim.x + threadIdx.x;
    if (c == 0) out[0] = 0.0f;
    if (c >= C_) return;
    float lat = centroids[2 * c] * DEG2RAD;
    float lon = centroids[2 * c + 1] * DEG2RAD;
    float cl = cosf(lat);
    int g = c >> 2, j = c & 3;
    ctq[12 * g + j]     = 0.5f * cl * cosf(lon);
    ctq[12 * g + 4 + j] = 0.5f * cl * sinf(lon);
    ctq[12 * g + 8 + j] = 0.5f * sinf(lat);
}

__device__ __forceinline__ float wave_red_add(float v) {
#pragma unroll
    for (int off = 32; off > 0; off >>= 1) v += __shfl_down(v, off, 64);
    return v;
}

__device__ __forceinline__ void accum_pair(float lv, float xv, float yv, float zv,
                                           float x1, float y1, float z1,
                                           float& W, float& T, float& S) {
    float dx = xv - x1, dy = yv - y1, dz = zv - z1;
    float a = fmaf(dx, dx, fmaf(dy, dy, dz * dz));   // = sin^2(theta/2)
    float s = __builtin_amdgcn_sqrtf(a);             // sin(theta/2)
    float p = fmaf(a, C1, C0);
    float w = __builtin_amdgcn_exp2f(s * p);         // exp(-dist/tau)
    W += w;
    T = fmaf(w, lv, T);
    S += __builtin_amdgcn_exp2f(lv * LOG2E);         // exp(l)
}

// One block per R_ rows; per 4-centroid group: 3 ct dwordx4 (one stream) +
// R_ logits dwordx4. Row losses atomically accumulated into out[0]/B.
__global__ __launch_bounds__(256, 8) void row_loss_kernel(
    const float* __restrict__ logits, const float* __restrict__ latlon,
    const float* __restrict__ ctq, float* __restrict__ out) {
    const int b0 = blockIdx.x * R_;

    float x1[R_], y1[R_], z1[R_];
#pragma unroll
    for (int r = 0; r < R_; ++r) {
        float lat = latlon[2 * (b0 + r)] * DEG2RAD;
        float lon = latlon[2 * (b0 + r) + 1] * DEG2RAD;
        float cl = cosf(lat);
        x1[r] = 0.5f * cl * cosf(lon);
        y1[r] = 0.5f * cl * sinf(lon);
        z1[r] = 0.5f * sinf(lat);
    }

    const float4* __restrict__ ct4 = (const float4*)ctq + 3 * (size_t)threadIdx.x;
    const float4* __restrict__ L0 =
        (const float4*)(logits + (size_t)b0 * C_) + threadIdx.x;
    const float4* __restrict__ L1 =
        (const float4*)(logits + (size_t)(b0 + 1) * C_) + threadIdx.x;

    float W[R_], T[R_], S[R_];
#pragma unroll
    for (int r = 0; r < R_; ++r) { W[r] = 0.f; T[r] = 0.f; S[r] = 0.f; }

#pragma unroll 2
    for (int i = 0; i < C_ / 4 / 256; ++i) {
        float4 X = ct4[0];
        float4 Y = ct4[1];
        float4 Z = ct4[2];
        float4 la = *L0;
        float4 lb = *L1;
        accum_pair(la.x, X.x, Y.x, Z.x, x1[0], y1[0], z1[0], W[0], T[0], S[0]);
        accum_pair(la.y, X.y, Y.y, Z.y, x1[0], y1[0], z1[0], W[0], T[0], S[0]);
        accum_pair(la.z, X.z, Y.z, Z.z, x1[0], y1[0], z1[0], W[0], T[0], S[0]);
        accum_pair(la.w, X.w, Y.w, Z.w, x1[0], y1[0], z1[0], W[0], T[0], S[0]);
        accum_pair(lb.x, X.x, Y.x, Z.x, x1[1], y1[1], z1[1], W[1], T[1], S[1]);
        accum_pair(lb.y, X.y, Y.y, Z.y, x1[1], y1[1], z1[1], W[1], T[1], S[1]);
        accum_pair(lb.z, X.z, Y.z, Z.z, x1[1], y1[1], z1[1], W[1], T[1], S[1]);
        accum_pair(lb.w, X.w, Y.w, Z.w, x1[1], y1[1], z1[1], W[1], T[1], S[1]);
        ct4 += 3 * 256;
        L0 += 256;
        L1 += 256;
    }

    __shared__ float red[3][R_][4];
    const int lane = threadIdx.x & 63, wv = threadIdx.x >> 6;
#pragma unroll
    for (int r = 0; r < R_; ++r) {
        float Wr = wave_red_add(W[r]);
        float Tr = wave_red_add(T[r]);
        float Sr = wave_red_add(S[r]);
        if (lane == 0) { red[0][r][wv] = Wr; red[1][r][wv] = Tr; red[2][r][wv] = Sr; }
    }
    __syncthreads();
    if (threadIdx.x < R_) {
        int r = threadIdx.x;
        float Wt = red[0][r][0] + red[0][r][1] + red[0][r][2] + red[0][r][3];
        float Tt = red[1][r][0] + red[1][r][1] + red[1][r][2] + red[1][r][3];
        float St = red[2][r][0] + red[2][r][1] + red[2][r][2] + red[2][r][3];
        Wt = fmaxf(Wt, 1e-30f);
        float loss = logf(St) - Tt / Wt;
        atomicAdd(out, loss * (1.0f / B_));
    }
}

extern "C" void kernel_launch(void* const* d_in, const int* in_sizes, int n_in,
                              void* d_out, int out_size, void* d_ws, size_t ws_size,
                              hipStream_t stream) {
    const float* pred_logits = (const float*)d_in[0];  // [B, C] f32
    const float* latlon      = (const float*)d_in[1];  // [B, 2] f32
    const float* centroids   = (const float*)d_in[2];  // [C, 2] f32
    // d_in[3] geocell_indices is unused by the reference.
    float* ctq = (float*)d_ws;           // 3*C floats, interleaved quads
    float* out = (float*)d_out;

    centroid_xyz_kernel<<<(C_ + 255) / 256, 256, 0, stream>>>(centroids, ctq, out);
    row_loss_kernel<<<B_ / R_, 256, 0, stream>>>(pred_logits, latlon, ctq, out);
}

// Round 7
// 46.761 us; speedup vs baseline: 1.2288x; 1.2288x over previous
//
#include <hip/hip_runtime.h>
#include <math.h>

namespace {
constexpr int B_ = 4096;
constexpr int C_ = 12288;
constexpr int R_ = 2;                    // rows per block
constexpr float DEG2RAD = 0.017453292519943295f;
constexpr float LOG2E = 1.4426950408889634f;
// w = exp(-2R*asin(s)/tau) = exp2(KN2*asin(s)), KN2 = -(2*6371/75)*log2(e)
constexpr float KN2 = -245.10427f;
// asin(s) ~= s*(1 + a/6), a = s^2. Truncation 0.075*s^5*|KN2|: ~1e-5 in the
// exponent at s=0.057 (w=1e-6) -> invisible. KN2*asin(s) = s*(C0 + C1*a).
constexpr float C0 = KN2;
constexpr float C1 = KN2 / 6.0f;
}

// Per-centroid HALF unit-sphere coords, interleaved per 4-centroid group:
// group g occupies 12 floats: [x0..x3][y0..y3][z0..z3] -> one address stream.
__global__ void centroid_xyz_kernel(const float* __restrict__ centroids,
                                    float* __restrict__ ctq) {
    int c = blockIdx.x * blockDim.x + threadIdx.x;
    if (c >= C_) return;
    float lat = centroids[2 * c] * DEG2RAD;
    float lon = centroids[2 * c + 1] * DEG2RAD;
    float cl = cosf(lat);
    int g = c >> 2, j = c & 3;
    ctq[12 * g + j]     = 0.5f * cl * cosf(lon);
    ctq[12 * g + 4 + j] = 0.5f * cl * sinf(lon);
    ctq[12 * g + 8 + j] = 0.5f * sinf(lat);
}

__device__ __forceinline__ float wave_red_add(float v) {
#pragma unroll
    for (int off = 32; off > 0; off >>= 1) v += __shfl_down(v, off, 64);
    return v;
}

__device__ __forceinline__ void accum_pair(float lv, float xv, float yv, float zv,
                                           float x1, float y1, float z1,
                                           float& W, float& T, float& S) {
    float dx = xv - x1, dy = yv - y1, dz = zv - z1;
    float a = fmaf(dx, dx, fmaf(dy, dy, dz * dz));   // = sin^2(theta/2)
    float s = __builtin_amdgcn_sqrtf(a);             // sin(theta/2)
    float p = fmaf(a, C1, C0);
    float w = __builtin_amdgcn_exp2f(s * p);         // exp(-dist/tau)
    W += w;
    T = fmaf(w, lv, T);
    S += __builtin_amdgcn_exp2f(lv * LOG2E);         // exp(l)
}

// One block per R_ rows; per 4-centroid group: 3 ct dwordx4 (one stream) +
// R_ logits dwordx4.
__global__ __launch_bounds__(256) void row_loss_kernel(
    const float* __restrict__ logits, const float* __restrict__ latlon,
    const float* __restrict__ ctq, float* __restrict__ row_loss) {
    const int b0 = blockIdx.x * R_;

    float x1[R_], y1[R_], z1[R_];
#pragma unroll
    for (int r = 0; r < R_; ++r) {
        float lat = latlon[2 * (b0 + r)] * DEG2RAD;
        float lon = latlon[2 * (b0 + r) + 1] * DEG2RAD;
        float cl = cosf(lat);
        x1[r] = 0.5f * cl * cosf(lon);
        y1[r] = 0.5f * cl * sinf(lon);
        z1[r] = 0.5f * sinf(lat);
    }

    const float4* __restrict__ ct4 = (const float4*)ctq + 3 * (size_t)threadIdx.x;
    const float4* __restrict__ L0 =
        (const float4*)(logits + (size_t)b0 * C_) + threadIdx.x;
    const float4* __restrict__ L1 =
        (const float4*)(logits + (size_t)(b0 + 1) * C_) + threadIdx.x;

    float W[R_], T[R_], S[R_];
#pragma unroll
    for (int r = 0; r < R_; ++r) { W[r] = 0.f; T[r] = 0.f; S[r] = 0.f; }

#pragma unroll 2
    for (int i = 0; i < C_ / 4 / 256; ++i) {
        float4 X = ct4[0];
        float4 Y = ct4[1];
        float4 Z = ct4[2];
        float4 la = *L0;
        float4 lb = *L1;
        accum_pair(la.x, X.x, Y.x, Z.x, x1[0], y1[0], z1[0], W[0], T[0], S[0]);
        accum_pair(la.y, X.y, Y.y, Z.y, x1[0], y1[0], z1[0], W[0], T[0], S[0]);
        accum_pair(la.z, X.z, Y.z, Z.z, x1[0], y1[0], z1[0], W[0], T[0], S[0]);
        accum_pair(la.w, X.w, Y.w, Z.w, x1[0], y1[0], z1[0], W[0], T[0], S[0]);
        accum_pair(lb.x, X.x, Y.x, Z.x, x1[1], y1[1], z1[1], W[1], T[1], S[1]);
        accum_pair(lb.y, X.y, Y.y, Z.y, x1[1], y1[1], z1[1], W[1], T[1], S[1]);
        accum_pair(lb.z, X.z, Y.z, Z.z, x1[1], y1[1], z1[1], W[1], T[1], S[1]);
        accum_pair(lb.w, X.w, Y.w, Z.w, x1[1], y1[1], z1[1], W[1], T[1], S[1]);
        ct4 += 3 * 256;
        L0 += 256;
        L1 += 256;
    }

    __shared__ float red[3][R_][4];
    const int lane = threadIdx.x & 63, wv = threadIdx.x >> 6;
#pragma unroll
    for (int r = 0; r < R_; ++r) {
        float Wr = wave_red_add(W[r]);
        float Tr = wave_red_add(T[r]);
        float Sr = wave_red_add(S[r]);
        if (lane == 0) { red[0][r][wv] = Wr; red[1][r][wv] = Tr; red[2][r][wv] = Sr; }
    }
    __syncthreads();
    if (threadIdx.x < R_) {
        int r = threadIdx.x;
        float Wt = red[0][r][0] + red[0][r][1] + red[0][r][2] + red[0][r][3];
        float Tt = red[1][r][0] + red[1][r][1] + red[1][r][2] + red[1][r][3];
        float St = red[2][r][0] + red[2][r][1] + red[2][r][2] + red[2][r][3];
        Wt = fmaxf(Wt, 1e-30f);
        row_loss[b0 + r] = logf(St) - Tt / Wt;
    }
}

__global__ __launch_bounds__(256) void final_reduce_kernel(
    const float* __restrict__ row_loss, float* __restrict__ out) {
    float s = 0.f;
    for (int i = threadIdx.x; i < B_; i += 256) s += row_loss[i];
    s = wave_red_add(s);
    __shared__ float red[4];
    const int lane = threadIdx.x & 63, wv = threadIdx.x >> 6;
    if (lane == 0) red[wv] = s;
    __syncthreads();
    if (threadIdx.x == 0)
        out[0] = (red[0] + red[1] + red[2] + red[3]) * (1.0f / B_);
}

extern "C" void kernel_launch(void* const* d_in, const int* in_sizes, int n_in,
                              void* d_out, int out_size, void* d_ws, size_t ws_size,
                              hipStream_t stream) {
    const float* pred_logits = (const float*)d_in[0];  // [B, C] f32
    const float* latlon      = (const float*)d_in[1];  // [B, 2] f32
    const float* centroids   = (const float*)d_in[2];  // [C, 2] f32
    // d_in[3] geocell_indices is unused by the reference.
    float* ctq      = (float*)d_ws;      // 3*C floats, interleaved quads
    float* row_loss = ctq + 3 * C_;      // B floats
    float* out      = (float*)d_out;

    centroid_xyz_kernel<<<(C_ + 255) / 256, 256, 0, stream>>>(centroids, ctq);
    row_loss_kernel<<<B_ / R_, 256, 0, stream>>>(pred_logits, latlon, ctq, row_loss);
    final_reduce_kernel<<<1, 256, 0, stream>>>(row_loss, out);
}